// Round 9
// baseline (1446.977 us; speedup 1.0000x reference)
//
#include <hip/hip_runtime.h>
#include <math.h>

#define T_STEPS 256
#define BATCH   256
#define DDIM    128
#define NH      10
#define NREG    4   // quarter statevector: 4 complex amps per lane per wave

// ---------- DPP helpers (VALU pipe; all proven R4-R8) ----------
template<int CTRL, int RMASK, int BMASK>
__device__ __forceinline__ float dppz(float x){
  return __int_as_float(__builtin_amdgcn_update_dpp(
      0, __float_as_int(x), CTRL, RMASK, BMASK, true));
}
template<int CTRL>
__device__ __forceinline__ float qperm(float x){
  int xi = __float_as_int(x);
  return __int_as_float(__builtin_amdgcn_update_dpp(xi, xi, CTRL, 0xF, 0xF, false));
}
__device__ __forceinline__ float lane_xor4(float x){
  int xi = __float_as_int(x);
  int t = __builtin_amdgcn_update_dpp(xi, xi, 0x104, 0xF, 0x5, false); // row_shl:4, banks {0,2}
  t     = __builtin_amdgcn_update_dpp(t,  xi, 0x114, 0xF, 0xA, false); // row_shr:4, banks {1,3}
  return __int_as_float(t);
}
__device__ __forceinline__ float lane_xor8(float x){
  int xi = __float_as_int(x);
  int t = __builtin_amdgcn_update_dpp(xi, xi, 0x108, 0xF, 0x3, false); // row_shl:8, banks {0,1}
  t     = __builtin_amdgcn_update_dpp(t,  xi, 0x118, 0xF, 0xC, false); // row_shr:8, banks {2,3}
  return __int_as_float(t);
}
__device__ __forceinline__ float red63(float v){
  v += dppz<0x111, 0xF, 0xF>(v);
  v += dppz<0x112, 0xF, 0xF>(v);
  v += dppz<0x114, 0xF, 0xE>(v);
  v += dppz<0x118, 0xF, 0xC>(v);
  v += dppz<0x142, 0xA, 0xF>(v);
  v += dppz<0x143, 0xC, 0xF>(v);
  return v;
}
__device__ __forceinline__ float wave_sum_b(float v){
  return __int_as_float(__builtin_amdgcn_readlane(__float_as_int(red63(v)), 63));
}

// RX on a reg-bit wire (bit BIT of the 2 reg bits). Pure VALU.
template<int BIT>
__device__ __forceinline__ void rx_reg(float c, float s, float* re, float* im){
  #pragma unroll
  for (int r = 0; r < NREG; ++r){
    if (r & (1 << BIT)) continue;
    const int r1 = r | (1 << BIT);
    float a0 = re[r], b0 = im[r], a1 = re[r1], b1 = im[r1];
    re[r]  = fmaf(c, a0,  s * b1);
    im[r]  = fmaf(c, b0, -s * a1);
    re[r1] = fmaf(c, a1,  s * b0);
    im[r1] = fmaf(c, b1, -s * a0);
  }
}
__device__ __forceinline__ void rx_lane(float c, float s, int mask, float* re, float* im){
  #pragma unroll
  for (int r = 0; r < NREG; ++r){
    float oa = __shfl_xor(re[r], mask, 64);
    float ob = __shfl_xor(im[r], mask, 64);
    re[r] = fmaf(c, re[r],  s * ob);
    im[r] = fmaf(c, im[r], -s * oa);
  }
}
#define RX_LANE_DPP(FETCH, cv, sv)                                             \
  { _Pragma("unroll")                                                          \
    for (int r = 0; r < NREG; ++r){                                            \
      float oa = FETCH(re[r]);                                                 \
      float ob = FETCH(im[r]);                                                 \
      re[r] = fmaf(cv, re[r],  sv * ob);                                       \
      im[r] = fmaf(cv, im[r], -sv * oa);                                       \
    } }
__device__ __forceinline__ float qp2(float x){ return qperm<0x4E>(x); }
__device__ __forceinline__ float qp1(float x){ return qperm<0xB1>(x); }

// ================= R9 layout =================
// Quarter-sim split: each gate-sim (1024 amps) across 4 waves; 256 amps/wave.
// Index bits: wires 0..5 -> lane bits 5..0; wire 6 -> wave bit W0; wire 7 ->
// wave bit W1; wires 8,9 -> reg bits 1,0. Block = 16 waves (4 gates x 4 subs),
// grid = 256 -> 4 waves/SIMD.
// Chain-CNOT betas (verified R8): beta_w = bit_{w-1}^bit_w (w>=2),
//   beta0 = bit0^bit9, beta1 = bit0^bit1^bit9. New coords:
//   b0=L5^R0 b1=L5^L4^R0 b2=L4^L3 b3=L3^L2 b4=L2^L1 b5=L1^L0
//   b6=L0^W0 b7=W0^W1 b8=W1^R1 b9=R1^R0
// Measurement S_0={1..9}, S_w={0..w}: lane masks as R8; wave parity: E6 -> W0,
// E0/E7/E8/E9 -> W0^W1; reg masks: E0,E9 -> 0b11, E8 -> 0b10.
// Wires 6+7 RX (both wave bits) FUSED into one LDS exchange:
//   U7*U6: a'' = c6c7*a - i*c7s6*b(sub^1) - i*c6s7*c(sub^2) - s6s7*d(sub^3).
__global__ void __launch_bounds__(1024)
qlstm_kernel(const float* __restrict__ inp, const float* __restrict__ rxp,
             const float* __restrict__ Wf, const float* __restrict__ bf,
             const float* __restrict__ Wi, const float* __restrict__ bi,
             const float* __restrict__ Wg, const float* __restrict__ bg,
             const float* __restrict__ Wo, const float* __restrict__ bo,
             float* __restrict__ out)
{
  const int b    = blockIdx.x;
  const int tid  = threadIdx.x;
  const int wv   = tid >> 6;        // 0..15
  const int g    = wv >> 2;         // gate 0..3 (f,i,g,o)
  const int sub  = wv & 3;          // quarter id: W1 W0
  const int W0   = sub & 1;
  const int W1   = (sub >> 1) & 1;
  const int lane = tid & 63;

  // exchange buffer: [gate][sub][chunk: re,im][lane] (lane stride 16B, clean)
  __shared__ float4 Sx[4][4][2][64];
  // measurement partials: [gate][sub][slot]; slots 10..63 stay 0 forever
  __shared__ float part[4][4][64];
  ((float*)part)[tid] = 0.f;        // 4*4*64 = 1024 = blockDim

  const float* Wp = (g == 0) ? Wf : (g == 1) ? Wi : (g == 2) ? Wg : Wo;
  const float* bp = (g == 0) ? bf : (g == 1) ? bi : (g == 2) ? bg : bo;

  float wA[NH], wB[NH], wC[NH], bT[NH];
  #pragma unroll
  for (int w = 0; w < NH; ++w){
    wA[w] = Wp[w*138 + lane];
    wB[w] = Wp[w*138 + 64 + lane];
    wC[w] = (lane < NH) ? Wp[w*138 + 128 + lane] : 0.f;
    bT[w] = bp[w] + rxp[w];
  }
  float pc[NH], ps[NH];
  #pragma unroll
  for (int w = 0; w < NH; ++w){
    float th = 0.5f * rxp[w];
    pc[w] = cosf(th);
    ps[w] = sinf(th);
  }
  // fused wire-6/7 exchange coefficients
  const float c67  = pc[6]*pc[7];
  const float c7s6 = pc[7]*ps[6];
  const float c6s7 = pc[6]*ps[7];
  const float s67  = ps[6]*ps[7];

  // ---- hoisted lane/wave constants ----
  const int l5 = (lane>>5)&1, l4 = (lane>>4)&1, l3 = (lane>>3)&1;
  const int l2 = (lane>>2)&1, l1 = (lane>>1)&1, l0 = lane&1;
  const int pb2 = l4^l3, pb3 = l3^l2, pb4 = l2^l1, pb5 = l1^l0;
  const int a0 = l5, a1 = l5^l4;
  const int a6w = l0 ^ W0;          // beta6
  const int b7w = W0 ^ W1;          // beta7 (wave-const)
  const int n_base = pb2 + pb3 + pb4 + pb5 + a6w + b7w;

  // phase constants (-i)^k per reg (step-invariant), 4 regs
  float cre4[NREG], cim4[NREG];
  #pragma unroll
  for (int r = 0; r < NREG; ++r){
    const int R0 = r&1, R1 = (r>>1)&1;
    int k = (n_base + (a0^R0) + (a1^R0) + (W1^R1) + (R1^R0)) & 3;
    cre4[r] = (k==0) ? 1.f : (k==2) ? -1.f : 0.f;
    cim4[r] = (k==1) ? -1.f : (k==3) ? 1.f : 0.f;
  }

  // measurement lane signs (identical to R8)
  const float ls0 = (__popc(lane & 0x1F) & 1) ? -1.f : 1.f;
  const float ls1 = (__popc(lane & 0x30) & 1) ? -1.f : 1.f;
  const float ls2 = (__popc(lane & 0x38) & 1) ? -1.f : 1.f;
  const float ls3 = (__popc(lane & 0x3C) & 1) ? -1.f : 1.f;
  const float ls4 = (__popc(lane & 0x3E) & 1) ? -1.f : 1.f;
  const float ls5 = (__popc(lane & 0x3F) & 1) ? -1.f : 1.f;

  // combine wave-signs per sub s, chosen per hidden unit (= lane):
  //   w in {1..5}: +1 ; w == 6: (-1)^{W0(s)} ; w in {0,7,8,9}: (-1)^{W0^W1}
  float sig[4];
  #pragma unroll
  for (int s = 0; s < 4; ++s){
    float sA = ((s ^ (s >> 1)) & 1) ? -1.f : 1.f;   // (-1)^{W0^W1}
    float sB = (s & 1) ? -1.f : 1.f;                // (-1)^{W0}
    sig[s] = (lane == 6) ? sB : ((lane == 0 || lane >= 7) ? sA : 1.f);
  }

  float h = 0.f, c = 0.f;   // lane j holds h_j, c_j redundantly in every wave

  const float* x0 = inp + (size_t)b * DDIM;
  float xa = x0[lane];
  float xb = x0[64 + lane];

  __syncthreads();

  #pragma unroll 1
  for (int t = 0; t < T_STEPS; ++t){
    float xaC = xa, xbC = xb;
    if (t + 1 < T_STEPS){
      const float* nx = inp + ((size_t)(t+1) * BATCH + b) * DDIM;
      xa = nx[lane];
      xb = nx[64 + lane];
    }

    // ---- gate pre-activation half-angles (redundant across a gate's 4 waves) ----
    float cs[NH], sn[NH];
    #pragma unroll
    for (int w = 0; w < NH; ++w){
      float p  = fmaf(xaC, wA[w], fmaf(xbC, wB[w], h * wC[w]));
      float th = 0.5f * (bT[w] + wave_sum_b(p));
      cs[w] = __cosf(th);
      sn[w] = __sinf(th);
    }

    // ---- build quarter-statevector: u[j] = prod-state(x+p) at K j ----
    float f2 = pb2 ? sn[2] : cs[2];
    float f3 = pb3 ? sn[3] : cs[3];
    float f4 = pb4 ? sn[4] : cs[4];
    float f5 = pb5 ? sn[5] : cs[5];
    float m_all = ((f2*f3)*(f4*f5)) * (a6w ? sn[6] : cs[6]) * (b7w ? sn[7] : cs[7]);

    float q0 = (a0 ? sn[0] : cs[0]) * (a1 ? sn[1] : cs[1]);
    float q1 = (a0 ? cs[0] : sn[0]) * (a1 ? cs[1] : sn[1]);
    float Z0 = m_all * q0, Z1 = m_all * q1;

    float u8_0 = W1 ? sn[8] : cs[8];   // beta8 = W1^R1, at R1=0
    float u8_1 = W1 ? cs[8] : sn[8];   // at R1=1

    float re[NREG], im[NREG];
    {
      // r: R1=r>>1, R0=r&1, beta9=R1^R0
      float m0 = (u8_0 * cs[9]) * Z0;   // r=0
      float m1 = (u8_0 * sn[9]) * Z1;   // r=1
      float m2 = (u8_1 * sn[9]) * Z0;   // r=2
      float m3 = (u8_1 * cs[9]) * Z1;   // r=3
      re[0] = m0 * cre4[0]; im[0] = m0 * cim4[0];
      re[1] = m1 * cre4[1]; im[1] = m1 * cim4[1];
      re[2] = m2 * cre4[2]; im[2] = m2 * cim4[2];
      re[3] = m3 * cre4[3]; im[3] = m3 * cim4[3];
    }

    // ---- RX(p): lane wires 0..5, reg wires 8,9 ----
    rx_lane(pc[0], ps[0], 32, re, im);
    rx_lane(pc[1], ps[1], 16, re, im);
    RX_LANE_DPP(lane_xor8, pc[2], ps[2])
    RX_LANE_DPP(lane_xor4, pc[3], ps[3])
    RX_LANE_DPP(qp2,       pc[4], ps[4])
    RX_LANE_DPP(qp1,       pc[5], ps[5])
    rx_reg<1>(pc[8], ps[8], re, im);
    rx_reg<0>(pc[9], ps[9], re, im);

    // ---- fused wire-6 + wire-7 RX: one LDS exchange with 3 partners ----
    Sx[g][sub][0][lane] = make_float4(re[0], re[1], re[2], re[3]);
    Sx[g][sub][1][lane] = make_float4(im[0], im[1], im[2], im[3]);
    __syncthreads();
    {
      float4 br = Sx[g][sub^1][0][lane], bi4 = Sx[g][sub^1][1][lane];
      float4 cr = Sx[g][sub^2][0][lane], ci4 = Sx[g][sub^2][1][lane];
      float4 dr = Sx[g][sub^3][0][lane], di4 = Sx[g][sub^3][1][lane];
      float bre[4] = {br.x,br.y,br.z,br.w}, bim[4] = {bi4.x,bi4.y,bi4.z,bi4.w};
      float cre_[4] = {cr.x,cr.y,cr.z,cr.w}, cim_[4] = {ci4.x,ci4.y,ci4.z,ci4.w};
      float dre[4] = {dr.x,dr.y,dr.z,dr.w}, dim_[4] = {di4.x,di4.y,di4.z,di4.w};
      #pragma unroll
      for (int r = 0; r < NREG; ++r){
        // new_re = c67*re + c7s6*im_b + c6s7*im_c - s67*re_d
        // new_im = c67*im - c7s6*re_b - c6s7*re_c - s67*im_d
        float nr = fmaf(c67, re[r], fmaf(c7s6, bim[r], fmaf(c6s7, cim_[r], -s67 * dre[r])));
        float ni = fmaf(c67, im[r], fmaf(-c7s6, bre[r], fmaf(-c6s7, cre_[r], -s67 * dim_[r])));
        re[r] = nr;
        im[r] = ni;
      }
    }

    // ---- PauliZ partials over this wave's 256 amps; totals land in lane 63 ----
    float tot = 0.f, q2m = 0.f, q3 = 0.f;
    #pragma unroll
    for (int r = 0; r < NREG; ++r){
      float p = fmaf(re[r], re[r], im[r]*im[r]);
      tot += p;
      q2m += (r & 2) ? -p : p;                    // reg mask 0b10 (R1)
      q3  += (((r >> 1) ^ r) & 1) ? -p : p;       // reg mask 0b11 (R1^R0)
    }
    float P0 = red63(ls0 * q3);
    float P1 = red63(ls1 * tot);
    float P2 = red63(ls2 * tot);
    float P3 = red63(ls3 * tot);
    float P4 = red63(ls4 * tot);
    float P5 = red63(ls5 * tot);   // serves E5 (+), E6 (W0 sign), E7 (W0^W1 sign)
    float P8 = red63(ls5 * q2m);
    float P9 = red63(ls5 * q3);
    if (lane == 63){
      float* pp = &part[g][sub][0];
      pp[0] = P0; pp[1] = P1; pp[2] = P2; pp[3] = P3; pp[4] = P4;
      pp[5] = P5; pp[6] = P5; pp[7] = P5; pp[8] = P8; pp[9] = P9;
    }
    __syncthreads();

    // ---- combine partials + activations + cell (every lane, every wave) ----
    float E0 = fmaf(sig[3], part[0][3][lane], fmaf(sig[2], part[0][2][lane],
               fmaf(sig[1], part[0][1][lane], sig[0] * part[0][0][lane])));
    float E1 = fmaf(sig[3], part[1][3][lane], fmaf(sig[2], part[1][2][lane],
               fmaf(sig[1], part[1][1][lane], sig[0] * part[1][0][lane])));
    float E2 = fmaf(sig[3], part[2][3][lane], fmaf(sig[2], part[2][2][lane],
               fmaf(sig[1], part[2][1][lane], sig[0] * part[2][0][lane])));
    float E3 = fmaf(sig[3], part[3][3][lane], fmaf(sig[2], part[3][2][lane],
               fmaf(sig[1], part[3][1][lane], sig[0] * part[3][0][lane])));
    float fv = 1.f / (1.f + __expf(-E0));
    float iv = 1.f / (1.f + __expf(-E1));
    float e2g = __expf(2.f * E2);
    float gv = (e2g - 1.f) / (e2g + 1.f);
    float ov = 1.f / (1.f + __expf(-E3));
    c = fmaf(fv, c, iv * gv);
    float e2c = __expf(2.f * c);
    h = ov * ((e2c - 1.f) / (e2c + 1.f));

    if (wv == 0 && lane < NH)
      out[((size_t)t * BATCH + b) * NH + lane] = h;
  }

  // hT, cT
  if (wv == 0 && lane < NH){
    const size_t ysN = (size_t)T_STEPS * BATCH * NH;
    out[ysN + (size_t)b * NH + lane]                      = h;
    out[ysN + (size_t)BATCH * NH + (size_t)b * NH + lane] = c;
  }
}

extern "C" void kernel_launch(void* const* d_in, const int* in_sizes, int n_in,
                              void* d_out, int out_size, void* d_ws, size_t ws_size,
                              hipStream_t stream)
{
  qlstm_kernel<<<BATCH, 1024, 0, stream>>>(
      (const float*)d_in[0], (const float*)d_in[1],
      (const float*)d_in[2], (const float*)d_in[3],
      (const float*)d_in[4], (const float*)d_in[5],
      (const float*)d_in[6], (const float*)d_in[7],
      (const float*)d_in[8], (const float*)d_in[9],
      (float*)d_out);
}

// Round 10
// 1380.168 us; speedup vs baseline: 1.0484x; 1.0484x over previous
//
#include <hip/hip_runtime.h>
#include <math.h>

#define T_STEPS 256
#define BATCH   256
#define DDIM    128
#define NH      10
#define NREG    4   // quarter statevector: 4 complex amps per lane per wave

// ---------- DPP helpers (VALU pipe; all proven R4-R9) ----------
template<int CTRL, int RMASK, int BMASK>
__device__ __forceinline__ float dppz(float x){
  return __int_as_float(__builtin_amdgcn_update_dpp(
      0, __float_as_int(x), CTRL, RMASK, BMASK, true));
}
template<int CTRL>
__device__ __forceinline__ float qperm(float x){
  int xi = __float_as_int(x);
  return __int_as_float(__builtin_amdgcn_update_dpp(xi, xi, CTRL, 0xF, 0xF, false));
}
__device__ __forceinline__ float lane_xor4(float x){
  int xi = __float_as_int(x);
  int t = __builtin_amdgcn_update_dpp(xi, xi, 0x104, 0xF, 0x5, false); // row_shl:4, banks {0,2}
  t     = __builtin_amdgcn_update_dpp(t,  xi, 0x114, 0xF, 0xA, false); // row_shr:4, banks {1,3}
  return __int_as_float(t);
}
__device__ __forceinline__ float lane_xor8(float x){
  int xi = __float_as_int(x);
  int t = __builtin_amdgcn_update_dpp(xi, xi, 0x108, 0xF, 0x3, false); // row_shl:8, banks {0,1}
  t     = __builtin_amdgcn_update_dpp(t,  xi, 0x118, 0xF, 0xC, false); // row_shr:8, banks {2,3}
  return __int_as_float(t);
}
__device__ __forceinline__ float red63(float v){
  v += dppz<0x111, 0xF, 0xF>(v);
  v += dppz<0x112, 0xF, 0xF>(v);
  v += dppz<0x114, 0xF, 0xE>(v);
  v += dppz<0x118, 0xF, 0xC>(v);
  v += dppz<0x142, 0xA, 0xF>(v);
  v += dppz<0x143, 0xC, 0xF>(v);
  return v;
}
__device__ __forceinline__ float wave_sum_b(float v){
  return __int_as_float(__builtin_amdgcn_readlane(__float_as_int(red63(v)), 63));
}

// RX on a reg-bit wire (bit BIT of the 2 reg bits). Pure VALU.
template<int BIT>
__device__ __forceinline__ void rx_reg(float c, float s, float* re, float* im){
  #pragma unroll
  for (int r = 0; r < NREG; ++r){
    if (r & (1 << BIT)) continue;
    const int r1 = r | (1 << BIT);
    float a0 = re[r], b0 = im[r], a1 = re[r1], b1 = im[r1];
    re[r]  = fmaf(c, a0,  s * b1);
    im[r]  = fmaf(c, b0, -s * a1);
    re[r1] = fmaf(c, a1,  s * b0);
    im[r1] = fmaf(c, b1, -s * a0);
  }
}
__device__ __forceinline__ void rx_lane(float c, float s, int mask, float* re, float* im){
  #pragma unroll
  for (int r = 0; r < NREG; ++r){
    float oa = __shfl_xor(re[r], mask, 64);
    float ob = __shfl_xor(im[r], mask, 64);
    re[r] = fmaf(c, re[r],  s * ob);
    im[r] = fmaf(c, im[r], -s * oa);
  }
}
#define RX_LANE_DPP(FETCH, cv, sv)                                             \
  { _Pragma("unroll")                                                          \
    for (int r = 0; r < NREG; ++r){                                            \
      float oa = FETCH(re[r]);                                                 \
      float ob = FETCH(im[r]);                                                 \
      re[r] = fmaf(cv, re[r],  sv * ob);                                       \
      im[r] = fmaf(cv, im[r], -sv * oa);                                       \
    } }
__device__ __forceinline__ float qp2(float x){ return qperm<0x4E>(x); }
__device__ __forceinline__ float qp1(float x){ return qperm<0xB1>(x); }

// ================= R10 = R9 structure + pinned register budget =================
// Quarter-sim split (verified correct R9): each gate-sim across 4 waves,
// 256 amps/wave; wires 0..5 -> lane bits, wires 6,7 -> wave bits W0,W1,
// wires 8,9 -> reg bits. Block = 16 waves, grid = 256 -> 4 waves/SIMD.
// R9 lesson: without waves_per_eu pin the allocator targeted 2 blocks/CU ->
// VGPR=64 -> ~28MB/dispatch scratch spill (WRITE_SIZE 4->22.5MB). Pin (4,4):
// 16 waves/block can't co-schedule 2 blocks/CU anyway; budget -> 128 VGPR.
__global__ void __launch_bounds__(1024)
__attribute__((amdgpu_waves_per_eu(4, 4)))
qlstm_kernel(const float* __restrict__ inp, const float* __restrict__ rxp,
             const float* __restrict__ Wf, const float* __restrict__ bf,
             const float* __restrict__ Wi, const float* __restrict__ bi,
             const float* __restrict__ Wg, const float* __restrict__ bg,
             const float* __restrict__ Wo, const float* __restrict__ bo,
             float* __restrict__ out)
{
  const int b    = blockIdx.x;
  const int tid  = threadIdx.x;
  const int wv   = tid >> 6;        // 0..15
  const int g    = wv >> 2;         // gate 0..3 (f,i,g,o)
  const int sub  = wv & 3;          // quarter id: bits (W1,W0)
  const int W0   = sub & 1;
  const int W1   = (sub >> 1) & 1;
  const int lane = tid & 63;

  // exchange buffer: [gate][sub][chunk: re,im][lane] (b128, conflict-free)
  __shared__ float4 Sx[4][4][2][64];
  // measurement partials: [gate][sub][slot]; slots 10..63 stay 0 forever
  __shared__ float part[4][4][64];
  ((float*)part)[tid] = 0.f;        // 4*4*64 = 1024 = blockDim

  const float* Wp = (g == 0) ? Wf : (g == 1) ? Wi : (g == 2) ? Wg : Wo;
  const float* bp = (g == 0) ? bf : (g == 1) ? bi : (g == 2) ? bg : bo;

  float wA[NH], wB[NH], wC[NH], bT[NH];
  #pragma unroll
  for (int w = 0; w < NH; ++w){
    wA[w] = Wp[w*138 + lane];
    wB[w] = Wp[w*138 + 64 + lane];
    wC[w] = (lane < NH) ? Wp[w*138 + 128 + lane] : 0.f;
    bT[w] = bp[w] + rxp[w];
  }
  float pc[NH], ps[NH];
  #pragma unroll
  for (int w = 0; w < NH; ++w){
    float th = 0.5f * rxp[w];
    pc[w] = cosf(th);
    ps[w] = sinf(th);
  }
  // fused wire-6/7 exchange coefficients
  const float c67  = pc[6]*pc[7];
  const float c7s6 = pc[7]*ps[6];
  const float c6s7 = pc[6]*ps[7];
  const float s67  = ps[6]*ps[7];

  // ---- hoisted lane/wave constants ----
  const int l5 = (lane>>5)&1, l4 = (lane>>4)&1, l3 = (lane>>3)&1;
  const int l2 = (lane>>2)&1, l1 = (lane>>1)&1, l0 = lane&1;
  const int pb2 = l4^l3, pb3 = l3^l2, pb4 = l2^l1, pb5 = l1^l0;
  const int a0 = l5, a1 = l5^l4;
  const int a6w = l0 ^ W0;          // beta6
  const int b7w = W0 ^ W1;          // beta7 (wave-const)
  const int n_base = pb2 + pb3 + pb4 + pb5 + a6w + b7w;

  // phase (-i)^k per reg packed into bitmasks (R6-verified trick; saves 6 regs)
  int odd4 = 0, neg4 = 0;
  #pragma unroll
  for (int r = 0; r < NREG; ++r){
    const int R0 = r&1, R1 = (r>>1)&1;
    int k = (n_base + (a0^R0) + (a1^R0) + (W1^R1) + (R1^R0)) & 3;
    if (k & 1) odd4 |= (1 << r);
    if (k == 1 || k == 2) neg4 |= (1 << r);
  }

  // measurement lane signs
  const float ls0 = (__popc(lane & 0x1F) & 1) ? -1.f : 1.f;
  const float ls1 = (__popc(lane & 0x30) & 1) ? -1.f : 1.f;
  const float ls2 = (__popc(lane & 0x38) & 1) ? -1.f : 1.f;
  const float ls3 = (__popc(lane & 0x3C) & 1) ? -1.f : 1.f;
  const float ls4 = (__popc(lane & 0x3E) & 1) ? -1.f : 1.f;
  const float ls5 = (__popc(lane & 0x3F) & 1) ? -1.f : 1.f;

  // combine wave-signs per sub s, per hidden unit (= lane):
  //   w in {1..5}: +1 ; w == 6: (-1)^{W0(s)} ; w in {0,7,8,9}: (-1)^{W0^W1}
  float sig[4];
  #pragma unroll
  for (int s = 0; s < 4; ++s){
    float sA = ((s ^ (s >> 1)) & 1) ? -1.f : 1.f;   // (-1)^{W0^W1}
    float sB = (s & 1) ? -1.f : 1.f;                // (-1)^{W0}
    sig[s] = (lane == 6) ? sB : ((lane == 0 || lane >= 7) ? sA : 1.f);
  }

  float h = 0.f, c = 0.f;   // lane j holds h_j, c_j redundantly in every wave

  const float* x0 = inp + (size_t)b * DDIM;
  float xa = x0[lane];
  float xb = x0[64 + lane];

  __syncthreads();

  #pragma unroll 1
  for (int t = 0; t < T_STEPS; ++t){
    float xaC = xa, xbC = xb;
    if (t + 1 < T_STEPS){
      const float* nx = inp + ((size_t)(t+1) * BATCH + b) * DDIM;
      xa = nx[lane];
      xb = nx[64 + lane];
    }

    // ---- gate pre-activation half-angles (redundant across a gate's 4 waves) ----
    float cs[NH], sn[NH];
    #pragma unroll
    for (int w = 0; w < NH; ++w){
      float p  = fmaf(xaC, wA[w], fmaf(xbC, wB[w], h * wC[w]));
      float th = 0.5f * (bT[w] + wave_sum_b(p));
      cs[w] = __cosf(th);
      sn[w] = __sinf(th);
    }

    // ---- build quarter-statevector: u[j] = prod-state(x+p) at K j ----
    float f2 = pb2 ? sn[2] : cs[2];
    float f3 = pb3 ? sn[3] : cs[3];
    float f4 = pb4 ? sn[4] : cs[4];
    float f5 = pb5 ? sn[5] : cs[5];
    float m_all = ((f2*f3)*(f4*f5)) * (a6w ? sn[6] : cs[6]) * (b7w ? sn[7] : cs[7]);

    float q0 = (a0 ? sn[0] : cs[0]) * (a1 ? sn[1] : cs[1]);
    float q1 = (a0 ? cs[0] : sn[0]) * (a1 ? cs[1] : sn[1]);
    float Z0 = m_all * q0, Z1 = m_all * q1;

    float u8_0 = W1 ? sn[8] : cs[8];   // beta8 = W1^R1, at R1=0
    float u8_1 = W1 ? cs[8] : sn[8];   // at R1=1

    float re[NREG], im[NREG];
    {
      float m4[NREG];
      m4[0] = (u8_0 * cs[9]) * Z0;
      m4[1] = (u8_0 * sn[9]) * Z1;
      m4[2] = (u8_1 * sn[9]) * Z0;
      m4[3] = (u8_1 * cs[9]) * Z1;
      #pragma unroll
      for (int r = 0; r < NREG; ++r){
        float sgn = (neg4 & (1 << r)) ? -m4[r] : m4[r];
        bool  od  = (odd4 & (1 << r)) != 0;
        re[r] = od ? 0.f : sgn;
        im[r] = od ? sgn : 0.f;
      }
    }

    // ---- RX(p): lane wires 0..5, reg wires 8,9 ----
    rx_lane(pc[0], ps[0], 32, re, im);
    rx_lane(pc[1], ps[1], 16, re, im);
    RX_LANE_DPP(lane_xor8, pc[2], ps[2])
    RX_LANE_DPP(lane_xor4, pc[3], ps[3])
    RX_LANE_DPP(qp2,       pc[4], ps[4])
    RX_LANE_DPP(qp1,       pc[5], ps[5])
    rx_reg<1>(pc[8], ps[8], re, im);
    rx_reg<0>(pc[9], ps[9], re, im);

    // ---- fused wire-6 + wire-7 RX: one LDS exchange with 3 partners ----
    Sx[g][sub][0][lane] = make_float4(re[0], re[1], re[2], re[3]);
    Sx[g][sub][1][lane] = make_float4(im[0], im[1], im[2], im[3]);
    __syncthreads();
    {
      float4 br = Sx[g][sub^1][0][lane], bi4 = Sx[g][sub^1][1][lane];
      float4 cr = Sx[g][sub^2][0][lane], ci4 = Sx[g][sub^2][1][lane];
      float4 dr = Sx[g][sub^3][0][lane], di4 = Sx[g][sub^3][1][lane];
      float bre[4] = {br.x,br.y,br.z,br.w}, bim[4] = {bi4.x,bi4.y,bi4.z,bi4.w};
      float cre_[4] = {cr.x,cr.y,cr.z,cr.w}, cim_[4] = {ci4.x,ci4.y,ci4.z,ci4.w};
      float dre[4] = {dr.x,dr.y,dr.z,dr.w}, dim_[4] = {di4.x,di4.y,di4.z,di4.w};
      #pragma unroll
      for (int r = 0; r < NREG; ++r){
        // new_re = c67*re + c7s6*im_b + c6s7*im_c - s67*re_d
        // new_im = c67*im - c7s6*re_b - c6s7*re_c - s67*im_d
        float nr = fmaf(c67, re[r], fmaf(c7s6, bim[r], fmaf(c6s7, cim_[r], -s67 * dre[r])));
        float ni = fmaf(c67, im[r], fmaf(-c7s6, bre[r], fmaf(-c6s7, cre_[r], -s67 * dim_[r])));
        re[r] = nr;
        im[r] = ni;
      }
    }

    // ---- PauliZ partials over this wave's 256 amps; totals land in lane 63 ----
    float tot = 0.f, q2m = 0.f, q3 = 0.f;
    #pragma unroll
    for (int r = 0; r < NREG; ++r){
      float p = fmaf(re[r], re[r], im[r]*im[r]);
      tot += p;
      q2m += (r & 2) ? -p : p;                    // reg mask 0b10 (R1)
      q3  += (((r >> 1) ^ r) & 1) ? -p : p;       // reg mask 0b11 (R1^R0)
    }
    float P0 = red63(ls0 * q3);
    float P1 = red63(ls1 * tot);
    float P2 = red63(ls2 * tot);
    float P3 = red63(ls3 * tot);
    float P4 = red63(ls4 * tot);
    float P5 = red63(ls5 * tot);   // serves E5 (+), E6 (W0 sign), E7 (W0^W1 sign)
    float P8 = red63(ls5 * q2m);
    float P9 = red63(ls5 * q3);
    if (lane == 63){
      float* pp = &part[g][sub][0];
      pp[0] = P0; pp[1] = P1; pp[2] = P2; pp[3] = P3; pp[4] = P4;
      pp[5] = P5; pp[6] = P5; pp[7] = P5; pp[8] = P8; pp[9] = P9;
    }
    __syncthreads();

    // ---- combine partials + activations + cell (every lane, every wave) ----
    float E0 = fmaf(sig[3], part[0][3][lane], fmaf(sig[2], part[0][2][lane],
               fmaf(sig[1], part[0][1][lane], sig[0] * part[0][0][lane])));
    float E1 = fmaf(sig[3], part[1][3][lane], fmaf(sig[2], part[1][2][lane],
               fmaf(sig[1], part[1][1][lane], sig[0] * part[1][0][lane])));
    float E2 = fmaf(sig[3], part[2][3][lane], fmaf(sig[2], part[2][2][lane],
               fmaf(sig[1], part[2][1][lane], sig[0] * part[2][0][lane])));
    float E3 = fmaf(sig[3], part[3][3][lane], fmaf(sig[2], part[3][2][lane],
               fmaf(sig[1], part[3][1][lane], sig[0] * part[3][0][lane])));
    float fv = 1.f / (1.f + __expf(-E0));
    float iv = 1.f / (1.f + __expf(-E1));
    float e2g = __expf(2.f * E2);
    float gv = (e2g - 1.f) / (e2g + 1.f);
    float ov = 1.f / (1.f + __expf(-E3));
    c = fmaf(fv, c, iv * gv);
    float e2c = __expf(2.f * c);
    h = ov * ((e2c - 1.f) / (e2c + 1.f));

    if (wv == 0 && lane < NH)
      out[((size_t)t * BATCH + b) * NH + lane] = h;
  }

  // hT, cT
  if (wv == 0 && lane < NH){
    const size_t ysN = (size_t)T_STEPS * BATCH * NH;
    out[ysN + (size_t)b * NH + lane]                      = h;
    out[ysN + (size_t)BATCH * NH + (size_t)b * NH + lane] = c;
  }
}

extern "C" void kernel_launch(void* const* d_in, const int* in_sizes, int n_in,
                              void* d_out, int out_size, void* d_ws, size_t ws_size,
                              hipStream_t stream)
{
  qlstm_kernel<<<BATCH, 1024, 0, stream>>>(
      (const float*)d_in[0], (const float*)d_in[1],
      (const float*)d_in[2], (const float*)d_in[3],
      (const float*)d_in[4], (const float*)d_in[5],
      (const float*)d_in[6], (const float*)d_in[7],
      (const float*)d_in[8], (const float*)d_in[9],
      (float*)d_out);
}

// Round 11
// 1102.008 us; speedup vs baseline: 1.3130x; 1.2524x over previous
//
#include <hip/hip_runtime.h>
#include <math.h>

#define T_STEPS 256
#define BATCH   256
#define DDIM    128
#define NH      10
#define NREG    4   // quarter statevector: 4 complex amps per lane per wave

// ---------- DPP helpers (VALU pipe; all proven R4-R10) ----------
template<int CTRL, int RMASK, int BMASK>
__device__ __forceinline__ float dppz(float x){
  return __int_as_float(__builtin_amdgcn_update_dpp(
      0, __float_as_int(x), CTRL, RMASK, BMASK, true));
}
template<int CTRL>
__device__ __forceinline__ float qperm(float x){
  int xi = __float_as_int(x);
  return __int_as_float(__builtin_amdgcn_update_dpp(xi, xi, CTRL, 0xF, 0xF, false));
}
__device__ __forceinline__ float lane_xor4(float x){
  int xi = __float_as_int(x);
  int t = __builtin_amdgcn_update_dpp(xi, xi, 0x104, 0xF, 0x5, false); // row_shl:4, banks {0,2}
  t     = __builtin_amdgcn_update_dpp(t,  xi, 0x114, 0xF, 0xA, false); // row_shr:4, banks {1,3}
  return __int_as_float(t);
}
__device__ __forceinline__ float lane_xor8(float x){
  int xi = __float_as_int(x);
  int t = __builtin_amdgcn_update_dpp(xi, xi, 0x108, 0xF, 0x3, false); // row_shl:8, banks {0,1}
  t     = __builtin_amdgcn_update_dpp(t,  xi, 0x118, 0xF, 0xC, false); // row_shr:8, banks {2,3}
  return __int_as_float(t);
}
__device__ __forceinline__ float red63(float v){
  v += dppz<0x111, 0xF, 0xF>(v);
  v += dppz<0x112, 0xF, 0xF>(v);
  v += dppz<0x114, 0xF, 0xE>(v);
  v += dppz<0x118, 0xF, 0xC>(v);
  v += dppz<0x142, 0xA, 0xF>(v);
  v += dppz<0x143, 0xC, 0xF>(v);
  return v;
}

template<int BIT>
__device__ __forceinline__ void rx_reg(float c, float s, float* re, float* im){
  #pragma unroll
  for (int r = 0; r < NREG; ++r){
    if (r & (1 << BIT)) continue;
    const int r1 = r | (1 << BIT);
    float a0 = re[r], b0 = im[r], a1 = re[r1], b1 = im[r1];
    re[r]  = fmaf(c, a0,  s * b1);
    im[r]  = fmaf(c, b0, -s * a1);
    re[r1] = fmaf(c, a1,  s * b0);
    im[r1] = fmaf(c, b1, -s * a0);
  }
}
__device__ __forceinline__ void rx_lane(float c, float s, int mask, float* re, float* im){
  #pragma unroll
  for (int r = 0; r < NREG; ++r){
    float oa = __shfl_xor(re[r], mask, 64);
    float ob = __shfl_xor(im[r], mask, 64);
    re[r] = fmaf(c, re[r],  s * ob);
    im[r] = fmaf(c, im[r], -s * oa);
  }
}
#define RX_LANE_DPP(FETCH, cv, sv)                                             \
  { _Pragma("unroll")                                                          \
    for (int r = 0; r < NREG; ++r){                                            \
      float oa = FETCH(re[r]);                                                 \
      float ob = FETCH(im[r]);                                                 \
      re[r] = fmaf(cv, re[r],  sv * ob);                                       \
      im[r] = fmaf(cv, im[r], -sv * oa);                                       \
    } }
__device__ __forceinline__ float qp2(float x){ return qperm<0x4E>(x); }
__device__ __forceinline__ float qp1(float x){ return qperm<0xB1>(x); }

// ================= R11 = R10 structure + register diet (anti-spill) =================
// Quarter-sim split (algebra verified R9/R10). New in R11:
//  - matvec distributed: sub s owns wires {s, s+4, s+8}; lane 63 publishes
//    (cos,sin) of owned angles to LDS; everyone reads back (broadcast b64).
//    Same ladder, same lane-63 value, same trig => bit-identical numerics.
//  - cs/sn[20] and pc/ps[20] register arrays removed (LDS tables, incremental
//    consumption in build).  R9/R10 lesson: VGPR pinned at 64 by the backend
//    for 1024-thread blocks; ~122 live regs caused scratch spill (WRITE_SIZE
//    11-22 MB vs 4 MB ideal). Peak live now ~70.
//  - part packed float4-across-subs: combine reads 4 b128 instead of 16 b32.
__global__ void __launch_bounds__(1024, 4)
qlstm_kernel(const float* __restrict__ inp, const float* __restrict__ rxp,
             const float* __restrict__ Wf, const float* __restrict__ bf,
             const float* __restrict__ Wi, const float* __restrict__ bi,
             const float* __restrict__ Wg, const float* __restrict__ bg,
             const float* __restrict__ Wo, const float* __restrict__ bo,
             float* __restrict__ out)
{
  const int b    = blockIdx.x;
  const int tid  = threadIdx.x;
  const int wv   = tid >> 6;        // 0..15
  const int g    = wv >> 2;         // gate 0..3 (f,i,g,o)
  const int sub  = wv & 3;          // quarter id: bits (W1,W0)
  const int W0   = sub & 1;
  const int W1   = (sub >> 1) & 1;
  const int lane = tid & 63;

  __shared__ float4 Sx[4][4][2][64];     // exchange: [gate][sub][re|im][lane]
  __shared__ float4 part4[4][64];        // partials: [gate][slot].{x,y,z,w}=sub 0..3
  __shared__ float2 Ang[4][NH];          // data angles (cos,sin) per gate/wire
  __shared__ float2 Pp[NH];              // param RX (cos,sin) per wire (loop-invariant)

  // init LDS: partials to 0 (slots >=10 must stay 0), Pp table
  part4[tid & 3][(tid >> 2) & 63] = make_float4(0.f, 0.f, 0.f, 0.f);
  if (tid < NH){
    float th = 0.5f * rxp[tid];
    Pp[tid] = make_float2(cosf(th), sinf(th));
  }

  const float* Wp = (g == 0) ? Wf : (g == 1) ? Wi : (g == 2) ? Wg : Wo;
  const float* bp = (g == 0) ? bf : (g == 1) ? bi : (g == 2) ? bg : bo;

  // owned wires: sub, sub+4, sub+8 (subs 0,1 own 3; subs 2,3 own 2)
  const int nown = (sub < 2) ? 3 : 2;
  float wAo[3], wBo[3], wCo[3], bTo[3];
  #pragma unroll
  for (int k = 0; k < 3; ++k){
    int w = sub + 4*k;
    if (k < nown){
      wAo[k] = Wp[w*138 + lane];
      wBo[k] = Wp[w*138 + 64 + lane];
      wCo[k] = (lane < NH) ? Wp[w*138 + 128 + lane] : 0.f;
      bTo[k] = bp[w] + rxp[w];
    } else { wAo[k] = wBo[k] = wCo[k] = bTo[k] = 0.f; }
  }

  // fused wire-6/7 exchange coefficients (loop-invariant, 4 regs)
  float c67, c7s6, c6s7, s67;
  {
    float t6 = 0.5f * rxp[6], t7 = 0.5f * rxp[7];
    float c6 = cosf(t6), s6 = sinf(t6), c7 = cosf(t7), s7 = sinf(t7);
    c67 = c6*c7; c7s6 = c7*s6; c6s7 = c6*s7; s67 = s6*s7;
  }

  // ---- hoisted lane/wave constants ----
  const int l5 = (lane>>5)&1, l4 = (lane>>4)&1, l3 = (lane>>3)&1;
  const int l2 = (lane>>2)&1, l1 = (lane>>1)&1, l0 = lane&1;
  const int pb2 = l4^l3, pb3 = l3^l2, pb4 = l2^l1, pb5 = l1^l0;
  const int a0 = l5, a1 = l5^l4;
  const int a6w = l0 ^ W0;          // beta6
  const int b7w = W0 ^ W1;          // beta7 (wave-const)
  const int n_base = pb2 + pb3 + pb4 + pb5 + a6w + b7w;

  // phase (-i)^k per reg packed into bitmasks (R6/R10-verified)
  int odd4 = 0, neg4 = 0;
  #pragma unroll
  for (int r = 0; r < NREG; ++r){
    const int R0 = r&1, R1 = (r>>1)&1;
    int k = (n_base + (a0^R0) + (a1^R0) + (W1^R1) + (R1^R0)) & 3;
    if (k & 1) odd4 |= (1 << r);
    if (k == 1 || k == 2) neg4 |= (1 << r);
  }

  // measurement lane signs
  const float ls0 = (__popc(lane & 0x1F) & 1) ? -1.f : 1.f;
  const float ls1 = (__popc(lane & 0x30) & 1) ? -1.f : 1.f;
  const float ls2 = (__popc(lane & 0x38) & 1) ? -1.f : 1.f;
  const float ls3 = (__popc(lane & 0x3C) & 1) ? -1.f : 1.f;
  const float ls4 = (__popc(lane & 0x3E) & 1) ? -1.f : 1.f;
  const float ls5 = (__popc(lane & 0x3F) & 1) ? -1.f : 1.f;

  // combine wave-signs per sub s, per hidden unit (= lane)
  float sig[4];
  #pragma unroll
  for (int s = 0; s < 4; ++s){
    float sA = ((s ^ (s >> 1)) & 1) ? -1.f : 1.f;   // (-1)^{W0^W1}
    float sB = (s & 1) ? -1.f : 1.f;                // (-1)^{W0}
    sig[s] = (lane == 6) ? sB : ((lane == 0 || lane >= 7) ? sA : 1.f);
  }

  float h = 0.f, c = 0.f;   // lane j holds h_j, c_j redundantly in every wave

  const float* x0 = inp + (size_t)b * DDIM;
  float xa = x0[lane];
  float xb = x0[64 + lane];

  __syncthreads();

  #pragma unroll 1
  for (int t = 0; t < T_STEPS; ++t){
    float xaC = xa, xbC = xb;
    if (t + 1 < T_STEPS){
      const float* nx = inp + ((size_t)(t+1) * BATCH + b) * DDIM;
      xa = nx[lane];
      xb = nx[64 + lane];
    }

    // ---- phase 1: matvec for owned wires only; publish (cos,sin) to LDS ----
    #pragma unroll
    for (int k = 0; k < 3; ++k){
      if (k < nown){                          // wave-uniform guard
        float p = fmaf(xaC, wAo[k], fmaf(xbC, wBo[k], h * wCo[k]));
        float v = red63(p);
        if (lane == 63){
          float th = 0.5f * (bTo[k] + v);
          Ang[g][sub + 4*k] = make_float2(__cosf(th), __sinf(th));
        }
      }
    }
    __syncthreads();   // B1: angle table ready

    // ---- phase 2: build quarter-statevector (incremental angle consumption) ----
    float re[NREG], im[NREG];
    {
      float2 A2 = Ang[g][2], A3 = Ang[g][3], A4 = Ang[g][4], A5 = Ang[g][5];
      float f2 = pb2 ? A2.y : A2.x;
      float f3 = pb3 ? A3.y : A3.x;
      float f4 = pb4 ? A4.y : A4.x;
      float f5 = pb5 ? A5.y : A5.x;
      float m_all = (f2*f3)*(f4*f5);
      float2 A6 = Ang[g][6], A7 = Ang[g][7];
      m_all *= (a6w ? A6.y : A6.x) * (b7w ? A7.y : A7.x);

      float2 A0 = Ang[g][0], A1 = Ang[g][1];
      float q0 = (a0 ? A0.y : A0.x) * (a1 ? A1.y : A1.x);
      float q1 = (a0 ? A0.x : A0.y) * (a1 ? A1.x : A1.y);
      float Z0 = m_all * q0, Z1 = m_all * q1;

      float2 A8 = Ang[g][8], A9 = Ang[g][9];
      float u8_0 = W1 ? A8.y : A8.x;
      float u8_1 = W1 ? A8.x : A8.y;
      float m4[NREG];
      m4[0] = (u8_0 * A9.x) * Z0;
      m4[1] = (u8_0 * A9.y) * Z1;
      m4[2] = (u8_1 * A9.y) * Z0;
      m4[3] = (u8_1 * A9.x) * Z1;
      #pragma unroll
      for (int r = 0; r < NREG; ++r){
        float sgn = (neg4 & (1 << r)) ? -m4[r] : m4[r];
        bool  od  = (odd4 & (1 << r)) != 0;
        re[r] = od ? 0.f : sgn;
        im[r] = od ? sgn : 0.f;
      }
    }

    // ---- RX(p): lane wires 0..5, reg wires 8,9 (params read from LDS table) ----
    { float2 pw = Pp[0]; rx_lane(pw.x, pw.y, 32, re, im); }
    { float2 pw = Pp[1]; rx_lane(pw.x, pw.y, 16, re, im); }
    { float2 pw = Pp[2]; RX_LANE_DPP(lane_xor8, pw.x, pw.y) }
    { float2 pw = Pp[3]; RX_LANE_DPP(lane_xor4, pw.x, pw.y) }
    { float2 pw = Pp[4]; RX_LANE_DPP(qp2,       pw.x, pw.y) }
    { float2 pw = Pp[5]; RX_LANE_DPP(qp1,       pw.x, pw.y) }
    { float2 pw = Pp[8]; rx_reg<1>(pw.x, pw.y, re, im); }
    { float2 pw = Pp[9]; rx_reg<0>(pw.x, pw.y, re, im); }

    // ---- fused wire-6 + wire-7 RX: one LDS exchange with 3 partners ----
    Sx[g][sub][0][lane] = make_float4(re[0], re[1], re[2], re[3]);
    Sx[g][sub][1][lane] = make_float4(im[0], im[1], im[2], im[3]);
    __syncthreads();   // B2
    {
      float4 br = Sx[g][sub^1][0][lane], bi4 = Sx[g][sub^1][1][lane];
      float4 cr = Sx[g][sub^2][0][lane], ci4 = Sx[g][sub^2][1][lane];
      float4 dr = Sx[g][sub^3][0][lane], di4 = Sx[g][sub^3][1][lane];
      float bre[4] = {br.x,br.y,br.z,br.w}, bim[4] = {bi4.x,bi4.y,bi4.z,bi4.w};
      float cre_[4] = {cr.x,cr.y,cr.z,cr.w}, cim_[4] = {ci4.x,ci4.y,ci4.z,ci4.w};
      float dre[4] = {dr.x,dr.y,dr.z,dr.w}, dim_[4] = {di4.x,di4.y,di4.z,di4.w};
      #pragma unroll
      for (int r = 0; r < NREG; ++r){
        float nr = fmaf(c67, re[r], fmaf(c7s6, bim[r], fmaf(c6s7, cim_[r], -s67 * dre[r])));
        float ni = fmaf(c67, im[r], fmaf(-c7s6, bre[r], fmaf(-c6s7, cre_[r], -s67 * dim_[r])));
        re[r] = nr;
        im[r] = ni;
      }
    }

    // ---- PauliZ partials over this wave's 256 amps; totals land in lane 63 ----
    float tot = 0.f, q2m = 0.f, q3 = 0.f;
    #pragma unroll
    for (int r = 0; r < NREG; ++r){
      float p = fmaf(re[r], re[r], im[r]*im[r]);
      tot += p;
      q2m += (r & 2) ? -p : p;                    // reg mask 0b10 (R1)
      q3  += (((r >> 1) ^ r) & 1) ? -p : p;       // reg mask 0b11 (R1^R0)
    }
    float P0 = red63(ls0 * q3);
    float P1 = red63(ls1 * tot);
    float P2 = red63(ls2 * tot);
    float P3 = red63(ls3 * tot);
    float P4 = red63(ls4 * tot);
    float P5 = red63(ls5 * tot);   // serves E5 (+), E6 (W0 sign), E7 (W0^W1 sign)
    float P8 = red63(ls5 * q2m);
    float P9 = red63(ls5 * q3);
    if (lane == 63){
      float* base = (float*)&part4[g][0];         // [slot].{comp=sub}
      base[0*4+sub] = P0; base[1*4+sub] = P1; base[2*4+sub] = P2;
      base[3*4+sub] = P3; base[4*4+sub] = P4; base[5*4+sub] = P5;
      base[6*4+sub] = P5; base[7*4+sub] = P5; base[8*4+sub] = P8;
      base[9*4+sub] = P9;
    }
    __syncthreads();   // B3

    // ---- combine partials + activations + cell (every lane, every wave) ----
    float4 p0 = part4[0][lane];
    float4 p1 = part4[1][lane];
    float4 p2 = part4[2][lane];
    float4 p3 = part4[3][lane];
    float E0 = fmaf(sig[3], p0.w, fmaf(sig[2], p0.z, fmaf(sig[1], p0.y, sig[0]*p0.x)));
    float E1 = fmaf(sig[3], p1.w, fmaf(sig[2], p1.z, fmaf(sig[1], p1.y, sig[0]*p1.x)));
    float E2 = fmaf(sig[3], p2.w, fmaf(sig[2], p2.z, fmaf(sig[1], p2.y, sig[0]*p2.x)));
    float E3 = fmaf(sig[3], p3.w, fmaf(sig[2], p3.z, fmaf(sig[1], p3.y, sig[0]*p3.x)));
    float fv = 1.f / (1.f + __expf(-E0));
    float iv = 1.f / (1.f + __expf(-E1));
    float e2g = __expf(2.f * E2);
    float gv = (e2g - 1.f) / (e2g + 1.f);
    float ov = 1.f / (1.f + __expf(-E3));
    c = fmaf(fv, c, iv * gv);
    float e2c = __expf(2.f * c);
    h = ov * ((e2c - 1.f) / (e2c + 1.f));

    if (wv == 0 && lane < NH)
      out[((size_t)t * BATCH + b) * NH + lane] = h;
  }

  // hT, cT
  if (wv == 0 && lane < NH){
    const size_t ysN = (size_t)T_STEPS * BATCH * NH;
    out[ysN + (size_t)b * NH + lane]                      = h;
    out[ysN + (size_t)BATCH * NH + (size_t)b * NH + lane] = c;
  }
}

extern "C" void kernel_launch(void* const* d_in, const int* in_sizes, int n_in,
                              void* d_out, int out_size, void* d_ws, size_t ws_size,
                              hipStream_t stream)
{
  qlstm_kernel<<<BATCH, 1024, 0, stream>>>(
      (const float*)d_in[0], (const float*)d_in[1],
      (const float*)d_in[2], (const float*)d_in[3],
      (const float*)d_in[4], (const float*)d_in[5],
      (const float*)d_in[6], (const float*)d_in[7],
      (const float*)d_in[8], (const float*)d_in[9],
      (float*)d_out);
}